// Round 5
// baseline (1297.969 us; speedup 1.0000x reference)
//
#include <hip/hip_runtime.h>
#include <hip/hip_bf16.h>

typedef __bf16 bf16x8 __attribute__((ext_vector_type(8)));
typedef float floatx4 __attribute__((ext_vector_type(4)));

__device__ __forceinline__ unsigned short f2bf(float f) {
  __bf16 b = (__bf16)f;
  return __builtin_bit_cast(unsigned short, b);
}

// ---------------------------------------------------------------------------
// Kernel 1: decode w1 bits -> bf16 {-1,0,+1} in a SWIZZLED fragment-major
// layout (K padded 784->800 with zeros):
//   off(row r, col c) = ((r>>4)*25 + (c>>5))*512 + (r&15)*32 + (c&31)
// -> each (16-row tile, 32-col chunk) is one contiguous 1KB run, so the
// GEMM's B-loads are perfectly coalesced 1KB wave-loads.
// ---------------------------------------------------------------------------
__global__ void decode_w1_kernel(const int* __restrict__ w1p,
                                 const int* __restrict__ m1p,
                                 unsigned short* __restrict__ w1d) {
  int t = blockIdx.x * 256 + threadIdx.x;
  if (t >= 256 * 100) return;
  int r = t / 100;
  int j = t - r * 100;
  unsigned short vals[8];
#pragma unroll
  for (int k = 0; k < 8; ++k) vals[k] = 0;
  if (j < 98) {
    unsigned int v = (unsigned int)w1p[r * 98 + j];
    unsigned int m = (unsigned int)m1p[r * 98 + j];
#pragma unroll
    for (int k = 0; k < 8; ++k) {           // MSB-first per byte (matches _unpack)
      unsigned int bit = (v >> (7 - k)) & 1u;
      unsigned int mk  = (m >> (7 - k)) & 1u;
      vals[k] = (unsigned short)(mk ? (bit ? 0x3F80u : 0xBF80u) : 0u);
    }
  }
  uint4 pack;
  pack.x = (unsigned)vals[0] | ((unsigned)vals[1] << 16);
  pack.y = (unsigned)vals[2] | ((unsigned)vals[3] << 16);
  pack.z = (unsigned)vals[4] | ((unsigned)vals[5] << 16);
  pack.w = (unsigned)vals[6] | ((unsigned)vals[7] << 16);
  int c0   = j * 8;                          // 16B-aligned (c0&31 in {0,8,16,24})
  int off  = (((r >> 4) * 25 + (c0 >> 5)) << 9) + ((r & 15) << 5) + (c0 & 31);
  *reinterpret_cast<uint4*>(w1d + off) = pack;
}

// ---------------------------------------------------------------------------
// Kernel 2: fused  h = relu(a1 * x@W1^T);  out = a2 * (h@W2^T)
// R5 = R4 structure + 2x waves + deeper prefetch:
//   * 512-thread blocks (8 waves), BM=32, LDS 51.7KB -> 3 blocks/CU
//     = 24 waves/CU (vs 12 in R4) to cover memory latency by TLP.
//   * B prefetch distance 2 (clamped in-bounds, no undef regs).
//   * phase-0 staging: 13 loads issued back-to-back, then convert+store.
// Wave w owns rows 0..31 (2 m-tiles, A shared via LDS) x cols w*32..+31
// (2 n-tiles) -> 4 MFMAs/chunk, acc = 16 VGPRs.
// mfma_f32_16x16x32_bf16: A[m=l15][k=quad*8+j], B^T[n=l15][k=quad*8+j],
// C/D col=l15, row=quad*4+reg (m89-verified).
// ---------------------------------------------------------------------------
#define W1TILE 12800  // shorts per 16-row swizzled tile: 25 chunks * 512
#define SLAB_LD 808   // shorts; rows 1616B (16B-aligned)
#define HS_LD 264
#define OFF_W2 (32 * HS_LD)   // W2s[16][264] after Hs[32][264] (overlay)

__global__ __launch_bounds__(512, 4) void fused_kernel(
    const float* __restrict__ x,
    const unsigned short* __restrict__ w1d,
    const int* __restrict__ w2p,
    const int* __restrict__ m2p,
    const float* __restrict__ a1p,
    const float* __restrict__ a2p,
    float* __restrict__ out) {
  // phase 1: x slab [32][808] bf16 = 51712 B.
  // phase 2 (overlay): Hs[32][264] + W2s[16][264] = 25344 B.
  __shared__ unsigned short smem[32 * SLAB_LD];

  const int tid  = threadIdx.x;
  const int wave = tid >> 6;    // 0..7
  const int lane = tid & 63;
  const int l15  = lane & 15;
  const int quad = lane >> 4;
  const int row0 = blockIdx.x * 32;

  // ---- phase 0: stage x slab (contiguous 100352B stream), cvt -> bf16 ----
  // 6272 float4s; 512 threads -> 12 full rounds + 128-thread tail.
  const float* xs = x + (size_t)row0 * 784;
  float4 v[13];
  const float4 z4 = (float4){0.f, 0.f, 0.f, 0.f};
#pragma unroll
  for (int i = 0; i < 13; ++i) {           // issue all loads back-to-back
    int f = i * 512 + tid;
    v[i] = (f < 6272) ? *reinterpret_cast<const float4*>(xs + (size_t)f * 4)
                      : z4;
  }
#pragma unroll
  for (int i = 0; i < 13; ++i) {           // convert + store
    int f = i * 512 + tid;
    if (f < 6272) {
      int r = f / 196;                     // 196 float4s per 784-fp32 row
      int c = (f - r * 196) * 4;
      ushort4 b;
      b.x = f2bf(v[i].x); b.y = f2bf(v[i].y);
      b.z = f2bf(v[i].z); b.w = f2bf(v[i].w);
      *reinterpret_cast<ushort4*>(&smem[r * SLAB_LD + c]) = b;
    }
  }
  if (tid < 128) {                         // zero K-pad cols 784..799
    int r = tid >> 2, g = tid & 3;
    ushort4 z = {0, 0, 0, 0};
    *reinterpret_cast<ushort4*>(&smem[r * SLAB_LD + 784 + g * 4]) = z;
  }
  __syncthreads();

  // ---- K-loop: 25 chunks, barrier-free, B prefetch distance 2 ----
  // Wave's B tiles: T = wave*2 + {0,1}; per-lane offset l15*32+quad*8 ->
  // the wave's 64 lanes cover one contiguous 1KB run per (tile,chunk).
  const unsigned short* wb0 =
      w1d + (size_t)(wave * 2) * W1TILE + l15 * 32 + quad * 8;
  const unsigned short* wb1 = wb0 + W1TILE;

  floatx4 acc[2][2];
#pragma unroll
  for (int i = 0; i < 2; ++i)
#pragma unroll
    for (int j = 0; j < 2; ++j) acc[i][j] = (floatx4){0.f, 0.f, 0.f, 0.f};

  bf16x8 bq[2][2];                          // [chunk parity][n-tile]
  bq[0][0] = *reinterpret_cast<const bf16x8*>(wb0);
  bq[0][1] = *reinterpret_cast<const bf16x8*>(wb1);
  bq[1][0] = *reinterpret_cast<const bf16x8*>(wb0 + 512);
  bq[1][1] = *reinterpret_cast<const bf16x8*>(wb1 + 512);

#pragma unroll 1
  for (int kc = 0; kc < 25; ++kc) {
    const int p = kc & 1;
    bf16x8 c0 = bq[p][0], c1 = bq[p][1];    // consume this chunk
    int kf = kc + 2;                         // prefetch distance 2
    if (kf > 24) kf = 24;                    // clamped: in-bounds, no undef
    bq[p][0] = *reinterpret_cast<const bf16x8*>(wb0 + kf * 512);
    bq[p][1] = *reinterpret_cast<const bf16x8*>(wb1 + kf * 512);
    const int ko = kc * 32 + quad * 8;
    bf16x8 a0 = *reinterpret_cast<const bf16x8*>(&smem[l15 * SLAB_LD + ko]);
    bf16x8 a1 =
        *reinterpret_cast<const bf16x8*>(&smem[(16 + l15) * SLAB_LD + ko]);
    acc[0][0] = __builtin_amdgcn_mfma_f32_16x16x32_bf16(a0, c0, acc[0][0], 0, 0, 0);
    acc[0][1] = __builtin_amdgcn_mfma_f32_16x16x32_bf16(a0, c1, acc[0][1], 0, 0, 0);
    acc[1][0] = __builtin_amdgcn_mfma_f32_16x16x32_bf16(a1, c0, acc[1][0], 0, 0, 0);
    acc[1][1] = __builtin_amdgcn_mfma_f32_16x16x32_bf16(a1, c1, acc[1][1], 0, 0, 0);
  }

  __syncthreads();   // all slab reads done before Hs overlays it

  // ---- epilogue layer 1: h = relu(a1*acc) -> Hs[32][264] bf16 ----
  const float a1s = a1p[0];
  const float a2s = a2p[0];
#pragma unroll
  for (int mi = 0; mi < 2; ++mi) {
#pragma unroll
    for (int nj = 0; nj < 2; ++nj) {
      int col   = wave * 32 + nj * 16 + l15;
      int rbase = mi * 16 + quad * 4;
#pragma unroll
      for (int r = 0; r < 4; ++r) {
        float h = fmaxf(a1s * acc[mi][nj][r], 0.f);
        smem[(rbase + r) * HS_LD + col] = f2bf(h);
      }
    }
  }
  // ---- decode w2 -> W2s[16][264] (rows 10..15 zero) ----
  if (tid < 320) {
    int r = tid >> 5, j = tid & 31;
    unsigned int vv = (unsigned int)w2p[r * 32 + j];
    unsigned int mm = (unsigned int)m2p[r * 32 + j];
#pragma unroll
    for (int k = 0; k < 8; ++k) {
      unsigned int bit = (vv >> (7 - k)) & 1u;
      unsigned int mk  = (mm >> (7 - k)) & 1u;
      smem[OFF_W2 + r * HS_LD + j * 8 + k] =
          (unsigned short)(mk ? (bit ? 0x3F80u : 0xBF80u) : 0u);
    }
  }
  if (tid < 256) {
#pragma unroll
    for (int r = 10; r < 16; ++r) smem[OFF_W2 + r * HS_LD + tid] = 0;
  }
  __syncthreads();

  // ---- layer 2: out[32][10] = Hs @ W2s^T; waves 0-1, 16 rows each, K=256 ---
  if (wave < 2) {
    floatx4 o2 = (floatx4){0.f, 0.f, 0.f, 0.f};
#pragma unroll
    for (int ks = 0; ks < 8; ++ks) {
      bf16x8 ha = *reinterpret_cast<const bf16x8*>(
          &smem[(wave * 16 + l15) * HS_LD + ks * 32 + quad * 8]);
      bf16x8 wv = *reinterpret_cast<const bf16x8*>(
          &smem[OFF_W2 + l15 * HS_LD + ks * 32 + quad * 8]);
      o2 = __builtin_amdgcn_mfma_f32_16x16x32_bf16(ha, wv, o2, 0, 0, 0);
    }
    if (l15 < 10) {
#pragma unroll
      for (int r = 0; r < 4; ++r) {
        int gr = row0 + wave * 16 + quad * 4 + r;
        out[(size_t)gr * 10 + l15] = a2s * o2[r];
      }
    }
  }
}

extern "C" void kernel_launch(void* const* d_in, const int* in_sizes, int n_in,
                              void* d_out, int out_size, void* d_ws, size_t ws_size,
                              hipStream_t stream) {
  const float* x   = (const float*)d_in[0];
  const int*   w1p = (const int*)d_in[1];
  const int*   m1p = (const int*)d_in[2];
  const float* a1  = (const float*)d_in[3];
  const int*   w2p = (const int*)d_in[4];
  const int*   m2p = (const int*)d_in[5];
  const float* a2  = (const float*)d_in[6];
  unsigned short* w1d = (unsigned short*)d_ws;  // 256*800 bf16 = 400 KB scratch
  float* out = (float*)d_out;

  decode_w1_kernel<<<100, 256, 0, stream>>>(w1p, m1p, w1d);
  fused_kernel<<<1024, 512, 0, stream>>>(x, w1d, w2p, m2p, a1, a2, out);
}